// Round 17
// baseline (1363.432 us; speedup 1.0000x reference)
//
#include <hip/hip_runtime.h>

// Problem constants
constexpr int B   = 16;
constexpr int N   = 768;
constexpr int FIN = 56;
constexpr int D   = 140;
constexpr int L   = 4;
constexpr int DF  = 128;
constexpr int NN  = N * N;        // 589824
constexpr int BND = B * N * D;    // 1720320
constexpr int BNN = B * NN;       // 9437184

// pooling split
constexpr int PROWS  = 16;            // rows per pooling block
constexpr int NCHUNK = N / PROWS;     // 48 partials per batch

// k_e tiling: K split 72+68 (16B-aligned chunk bases), 64x64 tiles
constexpr int NTILE = N / 64;         // 12
constexpr int NTRI  = NTILE * (NTILE + 1) / 2;  // 78 upper-triangle tiles

// k_athf2 tiling: 64i x 140d block, 4i x 12d micro-tile, 4-way j-split,
// both gates fused, 32-row j-chunks, DOUBLE-BUFFERED with async-stage split
// (issue global loads early, exp+LDS-write late) — round-16 showed LDS size
// is free (20.5KB vs 37.9KB both 13% occ) and the exposed staging latency
// between compute chunks is the cost.
// CORRECTNESS: att = exp(((adj>0)?E:-9e15)-M)*IS*adj for ALL entries
// (round-15 poisoned fully-masked-column lesson).
constexpr int JSPLIT = 4;
constexpr int JCH   = 32;             // j-chunk rows
constexpr int NCHK  = (N / JSPLIT) / JCH;   // 6 chunks per quarter

// partial pointers passed BY VALUE (graph-capture-safe kernel argument)
struct GatePtrs { float* g1[JSPLIT]; float* g2[JSPLIT]; };

// ---------------------------------------------------------------------------
// K1/K3: out[r][d] = in[r][:K] @ W[:K][d] (+bias), out stride D.
// Register-blocked 4r x 4d micro-tile, no LDS.
template<int K>
__global__ __launch_bounds__(256) void k_linrb(const float* __restrict__ in,
                                               const float* __restrict__ W,
                                               const float* __restrict__ bias,
                                               float* __restrict__ out) {
    constexpr int NDG = D / 4;        // 35 d-groups
    int idx = blockIdx.x * 256 + threadIdx.x;
    if (idx >= (B * N / 4) * NDG) return;
    int dt = idx % NDG;               // d fastest -> x broadcast, W coalesced
    int rt = idx / NDG;
    int r0 = rt * 4, d = dt * 4;

    float acc[4][4];
    float b0 = 0.f, b1 = 0.f, b2 = 0.f, b3 = 0.f;
    if (bias) { b0 = bias[d]; b1 = bias[d + 1]; b2 = bias[d + 2]; b3 = bias[d + 3]; }
#pragma unroll
    for (int s = 0; s < 4; ++s) {
        acc[s][0] = b0; acc[s][1] = b1; acc[s][2] = b2; acc[s][3] = b3;
    }

#pragma unroll 2
    for (int k = 0; k < K; k += 4) {
        float4 wv[4];
#pragma unroll
        for (int kk = 0; kk < 4; ++kk)
            wv[kk] = *reinterpret_cast<const float4*>(&W[(size_t)(k + kk) * D + d]);
#pragma unroll
        for (int s = 0; s < 4; ++s) {
            float4 xv = *reinterpret_cast<const float4*>(&in[(size_t)(r0 + s) * K + k]);
            float xa[4] = {xv.x, xv.y, xv.z, xv.w};
#pragma unroll
            for (int kk = 0; kk < 4; ++kk) {
                acc[s][0] += xa[kk] * wv[kk].x;
                acc[s][1] += xa[kk] * wv[kk].y;
                acc[s][2] += xa[kk] * wv[kk].z;
                acc[s][3] += xa[kk] * wv[kk].w;
            }
        }
    }

#pragma unroll
    for (int s = 0; s < 4; ++s) {
        float4 v = {acc[s][0], acc[s][1], acc[s][2], acc[s][3]};
        *reinterpret_cast<float4*>(&out[(size_t)(r0 + s) * D + d]) = v;
    }
}

// ---------------------------------------------------------------------------
// K2: adj2 = formulate(c_adjs2)  (elementwise, mask from valid/num_atoms)
__global__ __launch_bounds__(256) void k_adj2(const float* __restrict__ a2,
                                              const int* __restrict__ valid,
                                              const int* __restrict__ natoms,
                                              const float* __restrict__ mu,
                                              const float* __restrict__ dev,
                                              float* __restrict__ out) {
    int idx = blockIdx.x * 256 + threadIdx.x;
    if (idx >= BNN) return;
    int b   = idx / NN;
    int rem = idx - b * NN;
    int i   = rem / N;
    int j   = rem - i * N;
    float a = a2[idx];
    int vi = valid[b * N + i];
    int vj = valid[b * N + j];
    int n  = natoms[b];
    bool mask = (vi && !vj && (j < n)) || (vj && !vi && (i < n));
    float dmu = a - mu[0];
    float g = (a <= 10.f) ? expf(-dmu * dmu / dev[0]) : 0.f;
    out[idx] = mask ? g : a;
}

// ---------------------------------------------------------------------------
// K4: E[b,j,k] = hA[b,j,:]·h[b,k,:] + hA[b,k,:]·h[b,j,:]  (symmetric).
// Upper-triangle tiles launched directly (78 per batch, no idle blocks).
// Staging: 4x4 register block-transpose (float4 both sides).
__global__ __launch_bounds__(256) void k_e(const float* __restrict__ h,
                                           const float* __restrict__ hA,
                                           float* __restrict__ E) {
    int t = blockIdx.x;            // 0..77 linear upper-triangle index
    int b = blockIdx.y;
    int tj = 0, rem = t, rowlen = NTILE;
    while (rem >= rowlen) { rem -= rowlen; ++tj; --rowlen; }
    int tk = tj + rem;

    __shared__ float sJ[72][68];   // transposed j-tile chunk [c][j]
    __shared__ float sK[72][68];   // transposed k-tile chunk [c][j]
    int tid = threadIdx.x;
    int jg  = tid & 15;            // 16 j-groups x 4 j
    int kg  = tid >> 4;            // 16 k-groups x 4 k
    int j0 = tj * 64, k0 = tk * 64;
    const float* hb = h  + (size_t)b * N * D;
    const float* ab = hA + (size_t)b * N * D;

    float acc[4][4] = {};

    for (int r = 0; r < 4; ++r) {
        int ph = r >> 1;                  // 0: hA(j)·h(k), 1: h(j)·hA(k)
        int c0 = (r & 1) ? 72 : 0;
        int kc = (r & 1) ? 68 : 72;
        int ncb = kc >> 2;                // 18 or 17 c-blocks
        const float* uS = ph ? hb : ab;   // j-side source
        const float* vS = ph ? ab : hb;   // k-side source
        if (r) __syncthreads();
        // stage via 4x4 block transpose
        for (int idx = tid; idx < ncb * 16; idx += 256) {
            int cb = idx % ncb;
            int jb = (idx / ncb) * 4;     // 0,4,...,60
            int gc = c0 + cb * 4;
            float4 ru[4], rv[4];
#pragma unroll
            for (int s = 0; s < 4; ++s) {
                ru[s] = *reinterpret_cast<const float4*>(&uS[(size_t)(j0 + jb + s) * D + gc]);
                rv[s] = *reinterpret_cast<const float4*>(&vS[(size_t)(k0 + jb + s) * D + gc]);
            }
            float tu[4][4], tv[4][4];
#pragma unroll
            for (int s = 0; s < 4; ++s) {
                tu[s][0] = ru[s].x; tu[s][1] = ru[s].y; tu[s][2] = ru[s].z; tu[s][3] = ru[s].w;
                tv[s][0] = rv[s].x; tv[s][1] = rv[s].y; tv[s][2] = rv[s].z; tv[s][3] = rv[s].w;
            }
#pragma unroll
            for (int s = 0; s < 4; ++s) {
                float4 wu = {tu[0][s], tu[1][s], tu[2][s], tu[3][s]};
                float4 wv = {tv[0][s], tv[1][s], tv[2][s], tv[3][s]};
                *reinterpret_cast<float4*>(&sJ[cb * 4 + s][jb]) = wu;
                *reinterpret_cast<float4*>(&sK[cb * 4 + s][jb]) = wv;
            }
        }
        __syncthreads();
#pragma unroll 4
        for (int kk = 0; kk < kc; ++kk) {
            float4 ajv = *reinterpret_cast<const float4*>(&sJ[kk][jg * 4]);
            float4 akv = *reinterpret_cast<const float4*>(&sK[kk][kg * 4]);
            float aj[4] = {ajv.x, ajv.y, ajv.z, ajv.w};
            float ak[4] = {akv.x, akv.y, akv.z, akv.w};
#pragma unroll
            for (int i = 0; i < 4; ++i)
#pragma unroll
                for (int q = 0; q < 4; ++q) acc[i][q] += aj[i] * ak[q];
        }
    }

    float* Eb = E + (size_t)b * NN;
    int jb = j0 + jg * 4, kb = k0 + kg * 4;
#pragma unroll
    for (int i = 0; i < 4; ++i) {
        float4 v = {acc[i][0], acc[i][1], acc[i][2], acc[i][3]};
        *reinterpret_cast<float4*>(&Eb[(size_t)(jb + i) * N + kb]) = v;
    }
    // mirror: j-values per thread are contiguous -> also float4
#pragma unroll
    for (int q = 0; q < 4; ++q) {
        float4 v = {acc[0][q], acc[1][q], acc[2][q], acc[3][q]};
        *reinterpret_cast<float4*>(&Eb[(size_t)(kb + q) * N + jb]) = v;
    }
}

// ---------------------------------------------------------------------------
// K5: column softmax stats for BOTH adjacencies in one pass over E.
// Online/combine order identical to the original k_softmax -> bit-identical M,S.
__global__ __launch_bounds__(1024) void k_stats(const float* __restrict__ E,
                                                const float* __restrict__ a1,
                                                const float* __restrict__ a2,
                                                float* __restrict__ M1g, float* __restrict__ IS1g,
                                                float* __restrict__ M2g, float* __restrict__ IS2g) {
    int b    = blockIdx.y;
    int lane = threadIdx.x & 63;
    int js   = threadIdx.x >> 6;   // 0..15
    int k    = blockIdx.x * 64 + lane;
    const float* Eb = E  + (size_t)b * NN;
    const float* A1 = a1 + (size_t)b * NN;
    const float* A2 = a2 + (size_t)b * NN;

    float m1 = -3.0e38f, s1 = 0.f, m2 = -3.0e38f, s2 = 0.f;
    for (int j = js; j < N; j += 16) {
        float ev = Eb[(size_t)j * N + k];
        float v1 = A1[(size_t)j * N + k];
        float v2 = A2[(size_t)j * N + k];
        float x1 = (v1 > 0.f) ? ev : -9e15f;
        float x2 = (v2 > 0.f) ? ev : -9e15f;
        float n1 = fmaxf(m1, x1);
        s1 = s1 * __expf(m1 - n1) + __expf(x1 - n1);
        m1 = n1;
        float n2 = fmaxf(m2, x2);
        s2 = s2 * __expf(m2 - n2) + __expf(x2 - n2);
        m2 = n2;
    }
    __shared__ float sm1[16][64], ss1[16][64], sm2[16][64], ss2[16][64];
    sm1[js][lane] = m1; ss1[js][lane] = s1;
    sm2[js][lane] = m2; ss2[js][lane] = s2;
    __syncthreads();
    if (js == 0) {
        float M = sm1[0][lane], S = ss1[0][lane];
#pragma unroll
        for (int q = 1; q < 16; ++q) {
            float mq = sm1[q][lane], sq = ss1[q][lane];
            float nm = fmaxf(M, mq);
            S = S * __expf(M - nm) + sq * __expf(mq - nm);
            M = nm;
        }
        M1g[(size_t)b * N + k] = M;
        IS1g[(size_t)b * N + k] = 1.f / S;
        M = sm2[0][lane]; S = ss2[0][lane];
#pragma unroll
        for (int q = 1; q < 16; ++q) {
            float mq = sm2[q][lane], sq = ss2[q][lane];
            float nm = fmaxf(M, mq);
            S = S * __expf(M - nm) + sq * __expf(mq - nm);
            M = nm;
        }
        M2g[(size_t)b * N + k] = M;
        IS2g[(size_t)b * N + k] = 1.f / S;
    }
}

// ---------------------------------------------------------------------------
// K6: BOTH gates' fused softmax + partial ATT@h, one j-quarter per block.
// v3: double-buffered 32-row chunks + async-stage split. Per iteration:
//   (1) ISSUE next chunk's 12 global float4 loads (fly under compute),
//   (2) COMPUTE current chunk from LDS buf p,
//   (3) exp-transform + LDS-WRITE next chunk into buf p^1,  (4) barrier.
// Hazard-safe: buf p^1's last reader finished before the previous barrier.
// Math/order identical to round 16 (bit-identical output, poison-safe).
__global__ __launch_bounds__(192) void k_athf2(const float* __restrict__ E,
                                               const float* __restrict__ adj1,
                                               const float* __restrict__ adj2,
                                               const float* __restrict__ M1g,
                                               const float* __restrict__ IS1g,
                                               const float* __restrict__ M2g,
                                               const float* __restrict__ IS2g,
                                               const float* __restrict__ h,
                                               GatePtrs P) {
    int ti = blockIdx.x;           // 0..11 (64-row i-tile)
    int bz = blockIdx.y;
    int b  = bz >> 2;
    int js = bz & 3;
    __shared__ float sA1[2][JCH][68]; // ping-pong att1^T chunks (swizzled)
    __shared__ float sA2[2][JCH][68]; // ping-pong att2^T chunks
    __shared__ float sM1[192], sIS1[192], sM2[192], sIS2[192];
    int tid = threadIdx.x;
    int ig  = tid & 15;            // 16 i-groups x 4 i
    int dg  = tid >> 4;            // 12 d-groups x 12 d
    int i0  = ti * 64;
    const float* Eb = E    + (size_t)b * NN;
    const float* A1 = adj1 + (size_t)b * NN;
    const float* A2 = adj2 + (size_t)b * NN;
    const float* hb = h    + (size_t)b * N * D;
    int jbase = js * (N / JSPLIT);         // 192-j quarter

    sM1[tid]  = M1g[(size_t)b * N + jbase + tid];
    sIS1[tid] = IS1g[(size_t)b * N + jbase + tid];
    sM2[tid]  = M2g[(size_t)b * N + jbase + tid];
    sIS2[tid] = IS2g[(size_t)b * N + jbase + tid];
    __syncthreads();

    // staging thread coords (tid < 128: 8 j-blocks x 16 i-blocks)
    int  jb4 = tid & 7, ib4 = tid >> 3;
    bool stg = (tid < 128);
    float4 ev[4], a1v[4], a2v[4];     // in-flight staging registers

    auto LOADC = [&](int jtn) {       // issue global loads for chunk jtn
        if (stg && jtn < NCHK) {
            int j0n = jbase + jtn * JCH;
#pragma unroll
            for (int s = 0; s < 4; ++s) {
                size_t off = (size_t)(i0 + ib4 * 4 + s) * N + (j0n + jb4 * 4);
                ev[s]  = *reinterpret_cast<const float4*>(&Eb[off]);
                a1v[s] = *reinterpret_cast<const float4*>(&A1[off]);
                a2v[s] = *reinterpret_cast<const float4*>(&A2[off]);
            }
        }
    };
    auto WRITEC = [&](int jtn) {      // exp-transform + LDS write for chunk jtn
        if (stg && jtn < NCHK) {
            int p = jtn & 1;
            float mj1[4], is1[4], mj2[4], is2[4];
#pragma unroll
            for (int c = 0; c < 4; ++c) {
                int jj = jtn * JCH + jb4 * 4 + c;
                mj1[c] = sM1[jj]; is1[c] = sIS1[jj];
                mj2[c] = sM2[jj]; is2[c] = sIS2[jj];
            }
            float t1[4][4], t2[4][4];
#pragma unroll
            for (int s = 0; s < 4; ++s) {
                float ea[4] = {ev[s].x, ev[s].y, ev[s].z, ev[s].w};
                float b1[4] = {a1v[s].x, a1v[s].y, a1v[s].z, a1v[s].w};
                float b2[4] = {a2v[s].x, a2v[s].y, a2v[s].z, a2v[s].w};
#pragma unroll
                for (int c = 0; c < 4; ++c) {
                    float x1 = (b1[c] > 0.f) ? ea[c] : -9e15f;
                    float x2 = (b2[c] > 0.f) ? ea[c] : -9e15f;
                    t1[s][c] = __expf(x1 - mj1[c]) * is1[c] * b1[c];
                    t2[s][c] = __expf(x2 - mj2[c]) * is2[c] * b2[c];
                }
            }
#pragma unroll
            for (int c = 0; c < 4; ++c) {
                int row = jb4 * 4 + c;
                int col = (ib4 * 4) ^ (((row >> 2) & 7) << 2);   // swizzle
                float4 w1 = {t1[0][c], t1[1][c], t1[2][c], t1[3][c]};
                float4 w2 = {t2[0][c], t2[1][c], t2[2][c], t2[3][c]};
                *reinterpret_cast<float4*>(&sA1[p][row][col]) = w1;
                *reinterpret_cast<float4*>(&sA2[p][row][col]) = w2;
            }
        }
    };

    float ac1[4][12] = {};
    float ac2[4][12] = {};

    // prologue: stage chunk 0
    LOADC(0);
    WRITEC(0);
    __syncthreads();

    for (int jt = 0; jt < NCHK; ++jt) {
        int p  = jt & 1;
        int j0 = jbase + jt * JCH;
        LOADC(jt + 1);                 // loads in flight under the FMAs below
#pragma unroll 2
        for (int kk = 0; kk < JCH; ++kk) {
            int col = (ig * 4) ^ (((kk >> 2) & 7) << 2);         // swizzle
            float4 a4 = *reinterpret_cast<const float4*>(&sA1[p][kk][col]);
            float4 b4 = *reinterpret_cast<const float4*>(&sA2[p][kk][col]);
            const float* hrow = hb + (size_t)(j0 + kk) * D + dg * 12;
            float4 h0 = *reinterpret_cast<const float4*>(&hrow[0]);
            float4 h1 = *reinterpret_cast<const float4*>(&hrow[4]);
            float4 h2 = *reinterpret_cast<const float4*>(&hrow[8]);
            float ai[4]  = {a4.x, a4.y, a4.z, a4.w};
            float bi[4]  = {b4.x, b4.y, b4.z, b4.w};
            float hd[12] = {h0.x, h0.y, h0.z, h0.w,
                            h1.x, h1.y, h1.z, h1.w,
                            h2.x, h2.y, h2.z, h2.w};
#pragma unroll
            for (int i = 0; i < 4; ++i)
#pragma unroll
                for (int q = 0; q < 12; ++q) {
                    ac1[i][q] += ai[i] * hd[q];
                    ac2[i][q] += bi[i] * hd[q];
                }
        }
        WRITEC(jt + 1);                // write-late into the other buffer
        __syncthreads();
    }

    float* d1 = P.g1[js] + (size_t)b * N * D;
    float* d2 = P.g2[js] + (size_t)b * N * D;
#pragma unroll
    for (int s = 0; s < 4; ++s) {
        int row = i0 + ig * 4 + s;
#pragma unroll
        for (int t = 0; t < 3; ++t) {
            int cc = dg * 12 + t * 4;
            if (cc < D) {   // dg=11,t=2 (cols 140..143) discarded
                float4 v1 = {ac1[s][t * 4], ac1[s][t * 4 + 1],
                             ac1[s][t * 4 + 2], ac1[s][t * 4 + 3]};
                float4 v2 = {ac2[s][t * 4], ac2[s][t * 4 + 1],
                             ac2[s][t * 4 + 2], ac2[s][t * 4 + 3]};
                *reinterpret_cast<float4*>(&d1[(size_t)row * D + cc]) = v1;
                *reinterpret_cast<float4*>(&d2[(size_t)row * D + cc]) = v2;
            }
        }
    }
}

// ---------------------------------------------------------------------------
// K7: BOTH gates' combine in one pass (x read once, no g1 round-trip).
// hp1 = relu(sum g1 partials), hp2 = relu(sum g2 partials);
// x = (c2*x+(1-c2)*hp2) - (c1*x+(1-c1)*hp1)   — identical expressions/order
// to the two-dispatch path -> bit-identical.
__global__ __launch_bounds__(64) void k_gate2(float* __restrict__ x,
                                              GatePtrs P,
                                              const float* __restrict__ gw,
                                              const float* __restrict__ gb) {
    int row  = blockIdx.x;           // 0..B*N-1
    int lane = threadIdx.x;
    float* xr = x + (size_t)row * D;
    const float* q1[JSPLIT];
    const float* q2[JSPLIT];
#pragma unroll
    for (int e = 0; e < JSPLIT; ++e) {
        q1[e] = P.g1[e] + (size_t)row * D;
        q2[e] = P.g2[e] + (size_t)row * D;
    }
    float xv[3], h1v[3], h2v[3];
    float p1 = 0.f, p2 = 0.f;
#pragma unroll
    for (int q = 0; q < 3; ++q) {
        int d = lane + q * 64;
        xv[q] = 0.f; h1v[q] = 0.f; h2v[q] = 0.f;
        if (d < D) {
            xv[q] = xr[d];
            float s1 = q1[0][d];
#pragma unroll
            for (int e = 1; e < JSPLIT; ++e) s1 += q1[e][d];
            h1v[q] = fmaxf(s1, 0.f);
            float s2 = q2[0][d];
#pragma unroll
            for (int e = 1; e < JSPLIT; ++e) s2 += q2[e][d];
            h2v[q] = fmaxf(s2, 0.f);
            p1 += xv[q] * gw[d] + h1v[q] * gw[D + d];
            p2 += xv[q] * gw[d] + h2v[q] * gw[D + d];
        }
    }
#pragma unroll
    for (int off = 32; off; off >>= 1) {
        p1 += __shfl_xor(p1, off);
        p2 += __shfl_xor(p2, off);
    }
    float c1 = 1.f / (1.f + __expf(-(p1 + gb[0])));
    float c2 = 1.f / (1.f + __expf(-(p2 + gb[0])));
#pragma unroll
    for (int q = 0; q < 3; ++q) {
        int d = lane + q * 64;
        if (d < D) {
            float v1 = c1 * xv[q] + (1.f - c1) * h1v[q];
            float v2 = c2 * xv[q] + (1.f - c2) * h2v[q];
            xr[d] = v2 - v1;
        }
    }
}

// ---------------------------------------------------------------------------
// K8a: parallel ragged sum-pool, stage 1.
__global__ __launch_bounds__(256) void k_pool(const float* __restrict__ x,
                                              const int* __restrict__ natoms,
                                              float* __restrict__ part) {
    int c = blockIdx.x;              // chunk
    int b = blockIdx.y;              // batch
    int tid = threadIdx.x;
    if (tid >= D) return;
    int n  = natoms[b];
    int r0 = c * PROWS;
    int r1 = min(r0 + PROWS, n);
    const float* xb = x + (size_t)b * N * D;
    float acc = 0.f;
    for (int r = r0; r < r1; ++r) acc += xb[(size_t)r * D + tid];
    part[((size_t)b * NCHUNK + c) * D + tid] = acc;
}

// ---------------------------------------------------------------------------
// K8b: combine partials + 4-layer MLP + sigmoid. One block per batch.
__global__ __launch_bounds__(256) void k_final(const float* __restrict__ part,
                                               const float* __restrict__ w0, const float* __restrict__ b0,
                                               const float* __restrict__ w1, const float* __restrict__ b1,
                                               const float* __restrict__ w2, const float* __restrict__ b2,
                                               const float* __restrict__ w3, const float* __restrict__ b3,
                                               float* __restrict__ out) {
    int b   = blockIdx.x;
    int tid = threadIdx.x;
    __shared__ float pred[D];
    __shared__ float h0[DF], h1[DF], h2[DF];
    if (tid < D) {
        float acc = 0.f;
        const float* pb = part + (size_t)b * NCHUNK * D;
#pragma unroll 8
        for (int c = 0; c < NCHUNK; ++c) acc += pb[(size_t)c * D + tid];
        pred[tid] = acc;
    }
    __syncthreads();
    if (tid < DF) {
        float acc = b0[tid];
#pragma unroll 4
        for (int i = 0; i < D; ++i) acc += pred[i] * w0[i * DF + tid];
        h0[tid] = fmaxf(acc, 0.f);
    }
    __syncthreads();
    if (tid < DF) {
        float acc = b1[tid];
#pragma unroll 4
        for (int i = 0; i < DF; ++i) acc += h0[i] * w1[i * DF + tid];
        h1[tid] = fmaxf(acc, 0.f);
    }
    __syncthreads();
    if (tid < DF) {
        float acc = b2[tid];
#pragma unroll 4
        for (int i = 0; i < DF; ++i) acc += h1[i] * w2[i * DF + tid];
        h2[tid] = fmaxf(acc, 0.f);
    }
    __syncthreads();
    if (tid == 0) {
        float acc = b3[0];
        for (int i = 0; i < DF; ++i) acc += h2[i] * w3[i];
        out[b] = 1.f / (1.f + expf(-acc));
    }
}

// ---------------------------------------------------------------------------
extern "C" void kernel_launch(void* const* d_in, const int* in_sizes, int n_in,
                              void* d_out, int out_size, void* d_ws, size_t ws_size,
                              hipStream_t stream) {
    const float* c_hs  = (const float*)d_in[0];
    const float* adj1  = (const float*)d_in[1];
    const float* c_a2  = (const float*)d_in[2];
    const int*   valid = (const int*)d_in[3];
    const int*   nat   = (const int*)d_in[4];
    const float* Wemb  = (const float*)d_in[5];
    const float* gatW  = (const float*)d_in[6];
    const float* gatWb = (const float*)d_in[7];
    const float* gatA  = (const float*)d_in[8];
    const float* gatgw = (const float*)d_in[9];
    const float* gatgb = (const float*)d_in[10];
    const float* w0 = (const float*)d_in[11];
    const float* b0 = (const float*)d_in[12];
    const float* w1 = (const float*)d_in[13];
    const float* b1 = (const float*)d_in[14];
    const float* w2 = (const float*)d_in[15];
    const float* b2 = (const float*)d_in[16];
    const float* w3 = (const float*)d_in[17];
    const float* b3 = (const float*)d_in[18];
    const float* mu  = (const float*)d_in[19];
    const float* dev = (const float*)d_in[20];
    float* out = (float*)d_out;

    float* ws    = (float*)d_ws;
    float* adj2f = ws;                  // BNN
    float* Ebuf  = adj2f + BNN;         // BNN
    float* ATTws = Ebuf + BNN;          // BNN (hosts gate2 partials + stats)
    float* x     = ATTws + BNN;         // BND
    float* h     = x + BND;             // BND
    float* hA    = h + BND;             // BND  (dead after k_e -> gate1 partial 1)
    float* hp    = hA + BND;            // BND  (gate1 partial 0)
    float* g1    = hp + BND;            // BND  (gate1 partial 2)
    float* pC    = g1 + BND;            // BND  (gate1 partial 3)
    float* pD    = pC + BND;            // BND  (spare)
    // total: 3*BNN + 7*BND floats = 161.4 MB (unchanged)
    // gate2 partials in the ATTws slot (4*BND = 6.88M < BNN floats):
    float* p4 = ATTws;
    float* p5 = ATTws + (size_t)1 * BND;
    float* p6 = ATTws + (size_t)2 * BND;
    float* p7 = ATTws + (size_t)3 * BND;
    // stats arrays behind them (4*B*N floats):
    float* M1  = ATTws + (size_t)4 * BND;
    float* IS1 = M1 + (size_t)B * N;
    float* M2  = IS1 + (size_t)B * N;
    float* IS2 = M2 + (size_t)B * N;
    // partial pointers by value (kernel arg -> snapshotted at launch)
    GatePtrs P;
    P.g1[0] = hp; P.g1[1] = hA; P.g1[2] = g1; P.g1[3] = pC;
    P.g2[0] = p4; P.g2[1] = p5; P.g2[2] = p6; P.g2[3] = p7;
    // After the GAT loop, Ebuf is dead -> reuse as pooling partials
    float* part  = Ebuf;

    constexpr int LIN_GRID = (B * N / 4) * (D / 4) / 256;   // 420 blocks exactly

    k_linrb<FIN><<<LIN_GRID, 256, 0, stream>>>(c_hs, Wemb, nullptr, x);
    k_adj2<<<(BNN + 255) / 256, 256, 0, stream>>>(c_a2, valid, nat, mu, dev, adj2f);

    for (int l = 0; l < L; ++l) {
        const float* Wl  = gatW + (size_t)l * D * D;
        const float* Wbl = gatWb + (size_t)l * D;
        const float* Al  = gatA + (size_t)l * D * D;
        const float* gwl = gatgw + (size_t)l * 2 * D;
        const float* gbl = gatgb + l;

        k_linrb<D><<<LIN_GRID, 256, 0, stream>>>(x, Wl, Wbl, h);
        k_linrb<D><<<LIN_GRID, 256, 0, stream>>>(h, Al, nullptr, hA);
        k_e<<<dim3(NTRI, B), 256, 0, stream>>>(h, hA, Ebuf);

        // one pass over E computes column stats for BOTH adjacencies
        k_stats<<<dim3(N / 64, B), 1024, 0, stream>>>(Ebuf, adj1, adj2f,
                                                      M1, IS1, M2, IS2);

        // BOTH gates fused: E staged once, shared h loads, dbuf async-stage
        k_athf2<<<dim3(NTILE, B * JSPLIT), 192, 0, stream>>>(Ebuf, adj1, adj2f,
                                                             M1, IS1, M2, IS2,
                                                             h, P);
        // fused gate combine: x = gate2 - gate1 in one pass
        k_gate2<<<B * N, 64, 0, stream>>>(x, P, gwl, gbl);
    }

    // two-stage ragged pool, then MLP head
    k_pool<<<dim3(NCHUNK, B), 256, 0, stream>>>(x, nat, part);
    k_final<<<B, 256, 0, stream>>>(part, w0, b0, w1, b1, w2, b2, w3, b3, out);
}

// Round 18
// 1250.646 us; speedup vs baseline: 1.0902x; 1.0902x over previous
//
#include <hip/hip_runtime.h>

// Problem constants
constexpr int B   = 16;
constexpr int N   = 768;
constexpr int FIN = 56;
constexpr int D   = 140;
constexpr int L   = 4;
constexpr int DF  = 128;
constexpr int NN  = N * N;        // 589824
constexpr int BND = B * N * D;    // 1720320
constexpr int BNN = B * NN;       // 9437184

// pooling split
constexpr int PROWS  = 16;            // rows per pooling block
constexpr int NCHUNK = N / PROWS;     // 48 partials per batch

// k_e tiling: K split 72+68 (16B-aligned chunk bases), 64x64 tiles
constexpr int NTILE = N / 64;         // 12
constexpr int NTRI  = NTILE * (NTILE + 1) / 2;  // 78 upper-triangle tiles

// k_athf2 tiling: 64i x 140d block, 4i x 12d micro-tile, 4-way j-split,
// both gates fused, 32-row j-chunks (round-16 version — PLATEAU: prefetch,
// JSPLIT=8, i-split, LDS-halving, dbuf all null/negative; do not re-touch).
// CORRECTNESS: att = exp(((adj>0)?E:-9e15)-M)*IS*adj for ALL entries.
constexpr int JSPLIT = 4;
constexpr int JCH   = 32;             // j-chunk rows

// k_stats split: 192-block dispatch left 64 CUs idle (grid accounting).
// Two-stage: 768-block partial pass over 4 j-segments + tiny merge.
constexpr int KSEG = 4;               // j-segments for stats

// partial pointers passed BY VALUE (graph-capture-safe kernel argument)
struct GatePtrs { float* g1[JSPLIT]; float* g2[JSPLIT]; };

// ---------------------------------------------------------------------------
// K1/K3: out[r][d] = in[r][:K] @ W[:K][d] (+bias), out stride D.
// Register-blocked 4r x 4d micro-tile, no LDS.
template<int K>
__global__ __launch_bounds__(256) void k_linrb(const float* __restrict__ in,
                                               const float* __restrict__ W,
                                               const float* __restrict__ bias,
                                               float* __restrict__ out) {
    constexpr int NDG = D / 4;        // 35 d-groups
    int idx = blockIdx.x * 256 + threadIdx.x;
    if (idx >= (B * N / 4) * NDG) return;
    int dt = idx % NDG;               // d fastest -> x broadcast, W coalesced
    int rt = idx / NDG;
    int r0 = rt * 4, d = dt * 4;

    float acc[4][4];
    float b0 = 0.f, b1 = 0.f, b2 = 0.f, b3 = 0.f;
    if (bias) { b0 = bias[d]; b1 = bias[d + 1]; b2 = bias[d + 2]; b3 = bias[d + 3]; }
#pragma unroll
    for (int s = 0; s < 4; ++s) {
        acc[s][0] = b0; acc[s][1] = b1; acc[s][2] = b2; acc[s][3] = b3;
    }

#pragma unroll 2
    for (int k = 0; k < K; k += 4) {
        float4 wv[4];
#pragma unroll
        for (int kk = 0; kk < 4; ++kk)
            wv[kk] = *reinterpret_cast<const float4*>(&W[(size_t)(k + kk) * D + d]);
#pragma unroll
        for (int s = 0; s < 4; ++s) {
            float4 xv = *reinterpret_cast<const float4*>(&in[(size_t)(r0 + s) * K + k]);
            float xa[4] = {xv.x, xv.y, xv.z, xv.w};
#pragma unroll
            for (int kk = 0; kk < 4; ++kk) {
                acc[s][0] += xa[kk] * wv[kk].x;
                acc[s][1] += xa[kk] * wv[kk].y;
                acc[s][2] += xa[kk] * wv[kk].z;
                acc[s][3] += xa[kk] * wv[kk].w;
            }
        }
    }

#pragma unroll
    for (int s = 0; s < 4; ++s) {
        float4 v = {acc[s][0], acc[s][1], acc[s][2], acc[s][3]};
        *reinterpret_cast<float4*>(&out[(size_t)(r0 + s) * D + d]) = v;
    }
}

// ---------------------------------------------------------------------------
// K2: adj2 = formulate(c_adjs2)  (elementwise, mask from valid/num_atoms)
__global__ __launch_bounds__(256) void k_adj2(const float* __restrict__ a2,
                                              const int* __restrict__ valid,
                                              const int* __restrict__ natoms,
                                              const float* __restrict__ mu,
                                              const float* __restrict__ dev,
                                              float* __restrict__ out) {
    int idx = blockIdx.x * 256 + threadIdx.x;
    if (idx >= BNN) return;
    int b   = idx / NN;
    int rem = idx - b * NN;
    int i   = rem / N;
    int j   = rem - i * N;
    float a = a2[idx];
    int vi = valid[b * N + i];
    int vj = valid[b * N + j];
    int n  = natoms[b];
    bool mask = (vi && !vj && (j < n)) || (vj && !vi && (i < n));
    float dmu = a - mu[0];
    float g = (a <= 10.f) ? expf(-dmu * dmu / dev[0]) : 0.f;
    out[idx] = mask ? g : a;
}

// ---------------------------------------------------------------------------
// K4: E[b,j,k] = hA[b,j,:]·h[b,k,:] + hA[b,k,:]·h[b,j,:]  (symmetric).
// Upper-triangle tiles launched directly (78 per batch, no idle blocks).
// Staging: 4x4 register block-transpose (float4 both sides).
__global__ __launch_bounds__(256) void k_e(const float* __restrict__ h,
                                           const float* __restrict__ hA,
                                           float* __restrict__ E) {
    int t = blockIdx.x;            // 0..77 linear upper-triangle index
    int b = blockIdx.y;
    int tj = 0, rem = t, rowlen = NTILE;
    while (rem >= rowlen) { rem -= rowlen; ++tj; --rowlen; }
    int tk = tj + rem;

    __shared__ float sJ[72][68];   // transposed j-tile chunk [c][j]
    __shared__ float sK[72][68];   // transposed k-tile chunk [c][j]
    int tid = threadIdx.x;
    int jg  = tid & 15;            // 16 j-groups x 4 j
    int kg  = tid >> 4;            // 16 k-groups x 4 k
    int j0 = tj * 64, k0 = tk * 64;
    const float* hb = h  + (size_t)b * N * D;
    const float* ab = hA + (size_t)b * N * D;

    float acc[4][4] = {};

    for (int r = 0; r < 4; ++r) {
        int ph = r >> 1;                  // 0: hA(j)·h(k), 1: h(j)·hA(k)
        int c0 = (r & 1) ? 72 : 0;
        int kc = (r & 1) ? 68 : 72;
        int ncb = kc >> 2;                // 18 or 17 c-blocks
        const float* uS = ph ? hb : ab;   // j-side source
        const float* vS = ph ? ab : hb;   // k-side source
        if (r) __syncthreads();
        // stage via 4x4 block transpose
        for (int idx = tid; idx < ncb * 16; idx += 256) {
            int cb = idx % ncb;
            int jb = (idx / ncb) * 4;     // 0,4,...,60
            int gc = c0 + cb * 4;
            float4 ru[4], rv[4];
#pragma unroll
            for (int s = 0; s < 4; ++s) {
                ru[s] = *reinterpret_cast<const float4*>(&uS[(size_t)(j0 + jb + s) * D + gc]);
                rv[s] = *reinterpret_cast<const float4*>(&vS[(size_t)(k0 + jb + s) * D + gc]);
            }
            float tu[4][4], tv[4][4];
#pragma unroll
            for (int s = 0; s < 4; ++s) {
                tu[s][0] = ru[s].x; tu[s][1] = ru[s].y; tu[s][2] = ru[s].z; tu[s][3] = ru[s].w;
                tv[s][0] = rv[s].x; tv[s][1] = rv[s].y; tv[s][2] = rv[s].z; tv[s][3] = rv[s].w;
            }
#pragma unroll
            for (int s = 0; s < 4; ++s) {
                float4 wu = {tu[0][s], tu[1][s], tu[2][s], tu[3][s]};
                float4 wv = {tv[0][s], tv[1][s], tv[2][s], tv[3][s]};
                *reinterpret_cast<float4*>(&sJ[cb * 4 + s][jb]) = wu;
                *reinterpret_cast<float4*>(&sK[cb * 4 + s][jb]) = wv;
            }
        }
        __syncthreads();
#pragma unroll 4
        for (int kk = 0; kk < kc; ++kk) {
            float4 ajv = *reinterpret_cast<const float4*>(&sJ[kk][jg * 4]);
            float4 akv = *reinterpret_cast<const float4*>(&sK[kk][kg * 4]);
            float aj[4] = {ajv.x, ajv.y, ajv.z, ajv.w};
            float ak[4] = {akv.x, akv.y, akv.z, akv.w};
#pragma unroll
            for (int i = 0; i < 4; ++i)
#pragma unroll
                for (int q = 0; q < 4; ++q) acc[i][q] += aj[i] * ak[q];
        }
    }

    float* Eb = E + (size_t)b * NN;
    int jb = j0 + jg * 4, kb = k0 + kg * 4;
#pragma unroll
    for (int i = 0; i < 4; ++i) {
        float4 v = {acc[i][0], acc[i][1], acc[i][2], acc[i][3]};
        *reinterpret_cast<float4*>(&Eb[(size_t)(jb + i) * N + kb]) = v;
    }
    // mirror: j-values per thread are contiguous -> also float4
#pragma unroll
    for (int q = 0; q < 4; ++q) {
        float4 v = {acc[0][q], acc[1][q], acc[2][q], acc[3][q]};
        *reinterpret_cast<float4*>(&Eb[(size_t)(kb + q) * N + jb]) = v;
    }
}

// ---------------------------------------------------------------------------
// K5a: partial column-softmax stats over a 192-row j-segment, both adjs.
// Grid (12 k-tiles, 4 j-segs, B) = 768 blocks (was 192 -> 64 CUs idle).
// Per-slice online order and 16-way LDS merge identical to the original.
__global__ __launch_bounds__(1024) void k_statsp(const float* __restrict__ E,
                                                 const float* __restrict__ a1,
                                                 const float* __restrict__ a2,
                                                 float* __restrict__ Pm1, float* __restrict__ Ps1,
                                                 float* __restrict__ Pm2, float* __restrict__ Ps2) {
    int kt   = blockIdx.x;         // 0..11
    int seg  = blockIdx.y;         // 0..3
    int b    = blockIdx.z;
    int lane = threadIdx.x & 63;
    int js   = threadIdx.x >> 6;   // 0..15
    int k    = kt * 64 + lane;
    int j0   = seg * (N / KSEG);   // 192-row segment
    const float* Eb = E  + (size_t)b * NN;
    const float* A1 = a1 + (size_t)b * NN;
    const float* A2 = a2 + (size_t)b * NN;

    float m1 = -3.0e38f, s1 = 0.f, m2 = -3.0e38f, s2 = 0.f;
    for (int j = j0 + js; j < j0 + N / KSEG; j += 16) {
        float ev = Eb[(size_t)j * N + k];
        float v1 = A1[(size_t)j * N + k];
        float v2 = A2[(size_t)j * N + k];
        float x1 = (v1 > 0.f) ? ev : -9e15f;
        float x2 = (v2 > 0.f) ? ev : -9e15f;
        float n1 = fmaxf(m1, x1);
        s1 = s1 * __expf(m1 - n1) + __expf(x1 - n1);
        m1 = n1;
        float n2 = fmaxf(m2, x2);
        s2 = s2 * __expf(m2 - n2) + __expf(x2 - n2);
        m2 = n2;
    }
    __shared__ float sm1[16][64], ss1[16][64], sm2[16][64], ss2[16][64];
    sm1[js][lane] = m1; ss1[js][lane] = s1;
    sm2[js][lane] = m2; ss2[js][lane] = s2;
    __syncthreads();
    if (js == 0) {
        size_t o = ((size_t)seg * B + b) * N + k;
        float M = sm1[0][lane], S = ss1[0][lane];
#pragma unroll
        for (int q = 1; q < 16; ++q) {
            float mq = sm1[q][lane], sq = ss1[q][lane];
            float nm = fmaxf(M, mq);
            S = S * __expf(M - nm) + sq * __expf(mq - nm);
            M = nm;
        }
        Pm1[o] = M; Ps1[o] = S;
        M = sm2[0][lane]; S = ss2[0][lane];
#pragma unroll
        for (int q = 1; q < 16; ++q) {
            float mq = sm2[q][lane], sq = ss2[q][lane];
            float nm = fmaxf(M, mq);
            S = S * __expf(M - nm) + sq * __expf(mq - nm);
            M = nm;
        }
        Pm2[o] = M; Ps2[o] = S;
    }
}

// ---------------------------------------------------------------------------
// K5b: merge the 4 segment partials per (b,k), ascending seg order (same
// online-combine algebra). 48 blocks, trivially fast.
__global__ __launch_bounds__(256) void k_statsm(const float* __restrict__ Pm1,
                                                const float* __restrict__ Ps1,
                                                const float* __restrict__ Pm2,
                                                const float* __restrict__ Ps2,
                                                float* __restrict__ M1g, float* __restrict__ IS1g,
                                                float* __restrict__ M2g, float* __restrict__ IS2g) {
    int idx = blockIdx.x * 256 + threadIdx.x;   // b*N + k
    if (idx >= B * N) return;
    float M = Pm1[idx], S = Ps1[idx];
#pragma unroll
    for (int seg = 1; seg < KSEG; ++seg) {
        size_t o = (size_t)seg * B * N + idx;
        float mq = Pm1[o], sq = Ps1[o];
        float nm = fmaxf(M, mq);
        S = S * __expf(M - nm) + sq * __expf(mq - nm);
        M = nm;
    }
    M1g[idx] = M; IS1g[idx] = 1.f / S;
    M = Pm2[idx]; S = Ps2[idx];
#pragma unroll
    for (int seg = 1; seg < KSEG; ++seg) {
        size_t o = (size_t)seg * B * N + idx;
        float mq = Pm2[o], sq = Ps2[o];
        float nm = fmaxf(M, mq);
        S = S * __expf(M - nm) + sq * __expf(mq - nm);
        M = nm;
    }
    M2g[idx] = M; IS2g[idx] = 1.f / S;
}

// ---------------------------------------------------------------------------
// K6: BOTH gates' fused softmax + partial ATT@h, one j-quarter per block.
// Round-16 single-buffer version (plateau — do not re-touch).
__global__ __launch_bounds__(192) void k_athf2(const float* __restrict__ E,
                                               const float* __restrict__ adj1,
                                               const float* __restrict__ adj2,
                                               const float* __restrict__ M1g,
                                               const float* __restrict__ IS1g,
                                               const float* __restrict__ M2g,
                                               const float* __restrict__ IS2g,
                                               const float* __restrict__ h,
                                               GatePtrs P) {
    int ti = blockIdx.x;           // 0..11 (64-row i-tile)
    int bz = blockIdx.y;
    int b  = bz >> 2;
    int js = bz & 3;
    __shared__ float sA1[JCH][68]; // [j][i] att1^T chunk (cols XOR-swizzled)
    __shared__ float sA2[JCH][68]; // [j][i] att2^T chunk
    __shared__ float sM1[192], sIS1[192], sM2[192], sIS2[192];
    int tid = threadIdx.x;
    int ig  = tid & 15;            // 16 i-groups x 4 i
    int dg  = tid >> 4;            // 12 d-groups x 12 d
    int i0  = ti * 64;
    const float* Eb = E    + (size_t)b * NN;
    const float* A1 = adj1 + (size_t)b * NN;
    const float* A2 = adj2 + (size_t)b * NN;
    const float* hb = h    + (size_t)b * N * D;
    int jbase = js * (N / JSPLIT);         // 192-j quarter

    sM1[tid]  = M1g[(size_t)b * N + jbase + tid];
    sIS1[tid] = IS1g[(size_t)b * N + jbase + tid];
    sM2[tid]  = M2g[(size_t)b * N + jbase + tid];
    sIS2[tid] = IS2g[(size_t)b * N + jbase + tid];
    __syncthreads();

    float ac1[4][12] = {};
    float ac2[4][12] = {};

    for (int jt = 0; jt < (N / JSPLIT) / JCH; ++jt) {   // 6 chunks of 32
        int j0 = jbase + jt * JCH;
        int jl = jt * JCH;
        if (jt) __syncthreads();
        // stage BOTH att^T chunks: 4x4 block transpose, fused masked-softmax
        if (tid < 128) {
            int jb4 = tid & 7, ib4 = tid >> 3;
            float4 ev[4], a1v[4], a2v[4];
#pragma unroll
            for (int s = 0; s < 4; ++s) {
                size_t off = (size_t)(i0 + ib4 * 4 + s) * N + (j0 + jb4 * 4);
                ev[s]  = *reinterpret_cast<const float4*>(&Eb[off]);
                a1v[s] = *reinterpret_cast<const float4*>(&A1[off]);
                a2v[s] = *reinterpret_cast<const float4*>(&A2[off]);
            }
            float mj1[4], is1[4], mj2[4], is2[4];
#pragma unroll
            for (int c = 0; c < 4; ++c) {
                mj1[c] = sM1[jl + jb4 * 4 + c];
                is1[c] = sIS1[jl + jb4 * 4 + c];
                mj2[c] = sM2[jl + jb4 * 4 + c];
                is2[c] = sIS2[jl + jb4 * 4 + c];
            }
            float t1[4][4], t2[4][4];
#pragma unroll
            for (int s = 0; s < 4; ++s) {
                float ea[4] = {ev[s].x, ev[s].y, ev[s].z, ev[s].w};
                float b1[4] = {a1v[s].x, a1v[s].y, a1v[s].z, a1v[s].w};
                float b2[4] = {a2v[s].x, a2v[s].y, a2v[s].z, a2v[s].w};
#pragma unroll
                for (int c = 0; c < 4; ++c) {
                    float x1 = (b1[c] > 0.f) ? ea[c] : -9e15f;
                    float x2 = (b2[c] > 0.f) ? ea[c] : -9e15f;
                    t1[s][c] = __expf(x1 - mj1[c]) * is1[c] * b1[c];
                    t2[s][c] = __expf(x2 - mj2[c]) * is2[c] * b2[c];
                }
            }
#pragma unroll
            for (int c = 0; c < 4; ++c) {
                int row = jb4 * 4 + c;
                int col = (ib4 * 4) ^ (((row >> 2) & 7) << 2);   // swizzle
                float4 w1 = {t1[0][c], t1[1][c], t1[2][c], t1[3][c]};
                float4 w2 = {t2[0][c], t2[1][c], t2[2][c], t2[3][c]};
                *reinterpret_cast<float4*>(&sA1[row][col]) = w1;
                *reinterpret_cast<float4*>(&sA2[row][col]) = w2;
            }
        }
        __syncthreads();
#pragma unroll 2
        for (int kk = 0; kk < JCH; ++kk) {
            int col = (ig * 4) ^ (((kk >> 2) & 7) << 2);         // swizzle
            float4 a4 = *reinterpret_cast<const float4*>(&sA1[kk][col]);
            float4 b4 = *reinterpret_cast<const float4*>(&sA2[kk][col]);
            const float* hrow = hb + (size_t)(j0 + kk) * D + dg * 12;
            float4 h0 = *reinterpret_cast<const float4*>(&hrow[0]);
            float4 h1 = *reinterpret_cast<const float4*>(&hrow[4]);
            float4 h2 = *reinterpret_cast<const float4*>(&hrow[8]);
            float ai[4]  = {a4.x, a4.y, a4.z, a4.w};
            float bi[4]  = {b4.x, b4.y, b4.z, b4.w};
            float hd[12] = {h0.x, h0.y, h0.z, h0.w,
                            h1.x, h1.y, h1.z, h1.w,
                            h2.x, h2.y, h2.z, h2.w};
#pragma unroll
            for (int i = 0; i < 4; ++i)
#pragma unroll
                for (int q = 0; q < 12; ++q) {
                    ac1[i][q] += ai[i] * hd[q];
                    ac2[i][q] += bi[i] * hd[q];
                }
        }
    }

    float* d1 = P.g1[js] + (size_t)b * N * D;
    float* d2 = P.g2[js] + (size_t)b * N * D;
#pragma unroll
    for (int s = 0; s < 4; ++s) {
        int row = i0 + ig * 4 + s;
#pragma unroll
        for (int t = 0; t < 3; ++t) {
            int cc = dg * 12 + t * 4;
            if (cc < D) {   // dg=11,t=2 (cols 140..143) discarded
                float4 v1 = {ac1[s][t * 4], ac1[s][t * 4 + 1],
                             ac1[s][t * 4 + 2], ac1[s][t * 4 + 3]};
                float4 v2 = {ac2[s][t * 4], ac2[s][t * 4 + 1],
                             ac2[s][t * 4 + 2], ac2[s][t * 4 + 3]};
                *reinterpret_cast<float4*>(&d1[(size_t)row * D + cc]) = v1;
                *reinterpret_cast<float4*>(&d2[(size_t)row * D + cc]) = v2;
            }
        }
    }
}

// ---------------------------------------------------------------------------
// K7: BOTH gates' combine in one pass (x read once, no g1 round-trip).
__global__ __launch_bounds__(64) void k_gate2(float* __restrict__ x,
                                              GatePtrs P,
                                              const float* __restrict__ gw,
                                              const float* __restrict__ gb) {
    int row  = blockIdx.x;           // 0..B*N-1
    int lane = threadIdx.x;
    float* xr = x + (size_t)row * D;
    const float* q1[JSPLIT];
    const float* q2[JSPLIT];
#pragma unroll
    for (int e = 0; e < JSPLIT; ++e) {
        q1[e] = P.g1[e] + (size_t)row * D;
        q2[e] = P.g2[e] + (size_t)row * D;
    }
    float xv[3], h1v[3], h2v[3];
    float p1 = 0.f, p2 = 0.f;
#pragma unroll
    for (int q = 0; q < 3; ++q) {
        int d = lane + q * 64;
        xv[q] = 0.f; h1v[q] = 0.f; h2v[q] = 0.f;
        if (d < D) {
            xv[q] = xr[d];
            float s1 = q1[0][d];
#pragma unroll
            for (int e = 1; e < JSPLIT; ++e) s1 += q1[e][d];
            h1v[q] = fmaxf(s1, 0.f);
            float s2 = q2[0][d];
#pragma unroll
            for (int e = 1; e < JSPLIT; ++e) s2 += q2[e][d];
            h2v[q] = fmaxf(s2, 0.f);
            p1 += xv[q] * gw[d] + h1v[q] * gw[D + d];
            p2 += xv[q] * gw[d] + h2v[q] * gw[D + d];
        }
    }
#pragma unroll
    for (int off = 32; off; off >>= 1) {
        p1 += __shfl_xor(p1, off);
        p2 += __shfl_xor(p2, off);
    }
    float c1 = 1.f / (1.f + __expf(-(p1 + gb[0])));
    float c2 = 1.f / (1.f + __expf(-(p2 + gb[0])));
#pragma unroll
    for (int q = 0; q < 3; ++q) {
        int d = lane + q * 64;
        if (d < D) {
            float v1 = c1 * xv[q] + (1.f - c1) * h1v[q];
            float v2 = c2 * xv[q] + (1.f - c2) * h2v[q];
            xr[d] = v2 - v1;
        }
    }
}

// ---------------------------------------------------------------------------
// K8a: parallel ragged sum-pool, stage 1.
__global__ __launch_bounds__(256) void k_pool(const float* __restrict__ x,
                                              const int* __restrict__ natoms,
                                              float* __restrict__ part) {
    int c = blockIdx.x;              // chunk
    int b = blockIdx.y;              // batch
    int tid = threadIdx.x;
    if (tid >= D) return;
    int n  = natoms[b];
    int r0 = c * PROWS;
    int r1 = min(r0 + PROWS, n);
    const float* xb = x + (size_t)b * N * D;
    float acc = 0.f;
    for (int r = r0; r < r1; ++r) acc += xb[(size_t)r * D + tid];
    part[((size_t)b * NCHUNK + c) * D + tid] = acc;
}

// ---------------------------------------------------------------------------
// K8b: combine partials + 4-layer MLP + sigmoid. One block per batch.
__global__ __launch_bounds__(256) void k_final(const float* __restrict__ part,
                                               const float* __restrict__ w0, const float* __restrict__ b0,
                                               const float* __restrict__ w1, const float* __restrict__ b1,
                                               const float* __restrict__ w2, const float* __restrict__ b2,
                                               const float* __restrict__ w3, const float* __restrict__ b3,
                                               float* __restrict__ out) {
    int b   = blockIdx.x;
    int tid = threadIdx.x;
    __shared__ float pred[D];
    __shared__ float h0[DF], h1[DF], h2[DF];
    if (tid < D) {
        float acc = 0.f;
        const float* pb = part + (size_t)b * NCHUNK * D;
#pragma unroll 8
        for (int c = 0; c < NCHUNK; ++c) acc += pb[(size_t)c * D + tid];
        pred[tid] = acc;
    }
    __syncthreads();
    if (tid < DF) {
        float acc = b0[tid];
#pragma unroll 4
        for (int i = 0; i < D; ++i) acc += pred[i] * w0[i * DF + tid];
        h0[tid] = fmaxf(acc, 0.f);
    }
    __syncthreads();
    if (tid < DF) {
        float acc = b1[tid];
#pragma unroll 4
        for (int i = 0; i < DF; ++i) acc += h0[i] * w1[i * DF + tid];
        h1[tid] = fmaxf(acc, 0.f);
    }
    __syncthreads();
    if (tid < DF) {
        float acc = b2[tid];
#pragma unroll 4
        for (int i = 0; i < DF; ++i) acc += h1[i] * w2[i * DF + tid];
        h2[tid] = fmaxf(acc, 0.f);
    }
    __syncthreads();
    if (tid == 0) {
        float acc = b3[0];
        for (int i = 0; i < DF; ++i) acc += h2[i] * w3[i];
        out[b] = 1.f / (1.f + expf(-acc));
    }
}

// ---------------------------------------------------------------------------
extern "C" void kernel_launch(void* const* d_in, const int* in_sizes, int n_in,
                              void* d_out, int out_size, void* d_ws, size_t ws_size,
                              hipStream_t stream) {
    const float* c_hs  = (const float*)d_in[0];
    const float* adj1  = (const float*)d_in[1];
    const float* c_a2  = (const float*)d_in[2];
    const int*   valid = (const int*)d_in[3];
    const int*   nat   = (const int*)d_in[4];
    const float* Wemb  = (const float*)d_in[5];
    const float* gatW  = (const float*)d_in[6];
    const float* gatWb = (const float*)d_in[7];
    const float* gatA  = (const float*)d_in[8];
    const float* gatgw = (const float*)d_in[9];
    const float* gatgb = (const float*)d_in[10];
    const float* w0 = (const float*)d_in[11];
    const float* b0 = (const float*)d_in[12];
    const float* w1 = (const float*)d_in[13];
    const float* b1 = (const float*)d_in[14];
    const float* w2 = (const float*)d_in[15];
    const float* b2 = (const float*)d_in[16];
    const float* w3 = (const float*)d_in[17];
    const float* b3 = (const float*)d_in[18];
    const float* mu  = (const float*)d_in[19];
    const float* dev = (const float*)d_in[20];
    float* out = (float*)d_out;

    float* ws    = (float*)d_ws;
    float* adj2f = ws;                  // BNN
    float* Ebuf  = adj2f + BNN;         // BNN
    float* ATTws = Ebuf + BNN;          // BNN (gate2 partials + stats + seg partials)
    float* x     = ATTws + BNN;         // BND
    float* h     = x + BND;             // BND
    float* hA    = h + BND;             // BND  (dead after k_e -> gate1 partial 1)
    float* hp    = hA + BND;            // BND  (gate1 partial 0)
    float* g1    = hp + BND;            // BND  (gate1 partial 2)
    float* pC    = g1 + BND;            // BND  (gate1 partial 3)
    float* pD    = pC + BND;            // BND  (spare)
    // total: 3*BNN + 7*BND floats = 161.4 MB (unchanged)
    // gate2 partials in the ATTws slot (4*BND = 6.88M floats):
    float* p4 = ATTws;
    float* p5 = ATTws + (size_t)1 * BND;
    float* p6 = ATTws + (size_t)2 * BND;
    float* p7 = ATTws + (size_t)3 * BND;
    // merged stats arrays (4*B*N):
    float* M1  = ATTws + (size_t)4 * BND;
    float* IS1 = M1 + (size_t)B * N;
    float* M2  = IS1 + (size_t)B * N;
    float* IS2 = M2 + (size_t)B * N;
    // segment-partial stats (4 * KSEG*B*N = 196K floats; slot usage 7.13M < BNN)
    float* Pm1 = IS2 + (size_t)B * N;
    float* Ps1 = Pm1 + (size_t)KSEG * B * N;
    float* Pm2 = Ps1 + (size_t)KSEG * B * N;
    float* Ps2 = Pm2 + (size_t)KSEG * B * N;
    // partial pointers by value (kernel arg -> snapshotted at launch)
    GatePtrs P;
    P.g1[0] = hp; P.g1[1] = hA; P.g1[2] = g1; P.g1[3] = pC;
    P.g2[0] = p4; P.g2[1] = p5; P.g2[2] = p6; P.g2[3] = p7;
    // After the GAT loop, Ebuf is dead -> reuse as pooling partials
    float* part  = Ebuf;

    constexpr int LIN_GRID = (B * N / 4) * (D / 4) / 256;   // 420 blocks exactly

    k_linrb<FIN><<<LIN_GRID, 256, 0, stream>>>(c_hs, Wemb, nullptr, x);
    k_adj2<<<(BNN + 255) / 256, 256, 0, stream>>>(c_a2, valid, nat, mu, dev, adj2f);

    for (int l = 0; l < L; ++l) {
        const float* Wl  = gatW + (size_t)l * D * D;
        const float* Wbl = gatWb + (size_t)l * D;
        const float* Al  = gatA + (size_t)l * D * D;
        const float* gwl = gatgw + (size_t)l * 2 * D;
        const float* gbl = gatgb + l;

        k_linrb<D><<<LIN_GRID, 256, 0, stream>>>(x, Wl, Wbl, h);
        k_linrb<D><<<LIN_GRID, 256, 0, stream>>>(h, Al, nullptr, hA);
        k_e<<<dim3(NTRI, B), 256, 0, stream>>>(h, hA, Ebuf);

        // two-stage stats: 768-block partial pass + tiny merge
        k_statsp<<<dim3(NTILE, KSEG, B), 1024, 0, stream>>>(Ebuf, adj1, adj2f,
                                                            Pm1, Ps1, Pm2, Ps2);
        k_statsm<<<(B * N + 255) / 256, 256, 0, stream>>>(Pm1, Ps1, Pm2, Ps2,
                                                          M1, IS1, M2, IS2);

        // BOTH gates fused: E staged once, shared h loads, 2x intensity
        k_athf2<<<dim3(NTILE, B * JSPLIT), 192, 0, stream>>>(Ebuf, adj1, adj2f,
                                                             M1, IS1, M2, IS2,
                                                             h, P);
        // fused gate combine: x = gate2 - gate1 in one pass
        k_gate2<<<B * N, 64, 0, stream>>>(x, P, gwl, gbl);
    }

    // two-stage ragged pool, then MLP head
    k_pool<<<dim3(NCHUNK, B), 256, 0, stream>>>(x, nat, part);
    k_final<<<B, 256, 0, stream>>>(part, w0, b0, w1, b1, w2, b2, w3, b3, out);
}